// Round 11
// baseline (205.401 us; speedup 1.0000x reference)
//
#include <hip/hip_runtime.h>

#define D_MODEL 1024
#define D_STATE 16
#define DT_RANK 64
#define BATCH 2
#define SEQLEN 4096
#define NROWS (BATCH * SEQLEN)           // 8192
#define E_DIM 96
#define CH 32
#define NCH (SEQLEN / CH)                // 128

typedef short bf16x8 __attribute__((ext_vector_type(8)));
typedef float f32x4 __attribute__((ext_vector_type(4)));

// ---------------------------------------------------------------------------
// k_prep: Wx (96x1024 fp32) -> Wxbf (bf16 RNE, same layout)
//         W2 (1024x64 fp32) -> W2bf (bf16 RNE, same layout)
// ---------------------------------------------------------------------------
__global__ __launch_bounds__(256)
void k_prep(const float* __restrict__ Wx, const float* __restrict__ W2,
            unsigned short* __restrict__ Wxbf, unsigned short* __restrict__ W2bf) {
  const int bid = blockIdx.x;
  if (bid < 384) {                       // 96*1024 = 98304
    const int idx = bid * 256 + threadIdx.x;
    unsigned int u = __float_as_uint(Wx[idx]);
    u = (u + 0x7fffu + ((u >> 16) & 1u)) >> 16;   // RNE
    Wxbf[idx] = (unsigned short)u;
  } else {                               // 1024*64 = 65536
    const int idx = (bid - 384) * 256 + threadIdx.x;
    unsigned int u = __float_as_uint(W2[idx]);
    u = (u + 0x7fffu + ((u >> 16) & 1u)) >> 16;   // RNE
    W2bf[idx] = (unsigned short)u;
  }
}

// ---------------------------------------------------------------------------
// Kernel 1: dtBC = x @ Wx^T via bf16 MFMA 16x16x32, LDS-staged operands.
// Block: 4 waves, M-tile 64, KSPLIT=4. Rows padded to 72 bf16 (144B).
// D layout: row=(l>>4)*4+i, col=l&15  [m89-verified]
// ---------------------------------------------------------------------------
#define KSPLIT 4
#define KSEG (D_MODEL / KSPLIT)          // 256

__global__ __launch_bounds__(256)
void k_gemm1(const float* __restrict__ x, const unsigned short* __restrict__ Wxbf,
             float* __restrict__ parts) {
  __shared__ unsigned short sXb[64][72];   // 9.2 KB
  __shared__ unsigned short sWb[96][72];   // 13.8 KB
  const int tid = threadIdx.x;
  const int lane = tid & 63, w = tid >> 6;
  const int r = lane & 15, kq = lane >> 4;
  const int m0 = blockIdx.x * 64;
  const int ks0 = blockIdx.y * KSEG;

  f32x4 acc[6];
  #pragma unroll
  for (int j = 0; j < 6; ++j) acc[j] = (f32x4){0.f, 0.f, 0.f, 0.f};

  for (int kt = 0; kt < KSEG; kt += 64) {
    #pragma unroll
    for (int s = 0; s < 4; ++s) {
      const int f = s * 256 + tid;
      const int row = f >> 4, k4 = f & 15;
      const float4 v = *reinterpret_cast<const float4*>(
          &x[(size_t)(m0 + row) * D_MODEL + ks0 + kt + k4 * 4]);
      unsigned int u0, u1;
      asm("v_cvt_pk_bf16_f32 %0, %1, %2" : "=v"(u0) : "v"(v.x), "v"(v.y));
      asm("v_cvt_pk_bf16_f32 %0, %1, %2" : "=v"(u1) : "v"(v.z), "v"(v.w));
      *reinterpret_cast<uint2*>(&sXb[row][k4 * 4]) = make_uint2(u0, u1);
    }
    #pragma unroll
    for (int s = 0; s < 3; ++s) {
      const int f = s * 256 + tid;
      const int e = f >> 3, k8 = f & 7;
      *reinterpret_cast<uint4*>(&sWb[e][k8 * 8]) =
          *reinterpret_cast<const uint4*>(
              &Wxbf[(size_t)e * D_MODEL + ks0 + kt + k8 * 8]);
    }
    __syncthreads();
    #pragma unroll
    for (int ks = 0; ks < 2; ++ks) {
      const bf16x8 af = *reinterpret_cast<const bf16x8*>(
          &sXb[w * 16 + r][ks * 32 + kq * 8]);
      #pragma unroll
      for (int j = 0; j < 6; ++j) {
        const bf16x8 bf = *reinterpret_cast<const bf16x8*>(
            &sWb[j * 16 + r][ks * 32 + kq * 8]);
        acc[j] = __builtin_amdgcn_mfma_f32_16x16x32_bf16(af, bf, acc[j], 0, 0, 0);
      }
    }
    __syncthreads();
  }
  float* op = parts + (size_t)blockIdx.y * (NROWS * E_DIM);
  #pragma unroll
  for (int j = 0; j < 6; ++j)
    #pragma unroll
    for (int i = 0; i < 4; ++i)
      op[(size_t)(m0 + w * 16 + kq * 4 + i) * E_DIM + j * 16 + r] = acc[j][i];
}

// Sum KSPLIT partials -> dtBC (fp32); also emit dt_in_bf = bf16 of cols 0..63.
__global__ __launch_bounds__(256)
void k_reduce(const float* __restrict__ parts, float* __restrict__ dtBC,
              unsigned short* __restrict__ dt_in_bf) {
  const int i = blockIdx.x * 256 + threadIdx.x;     // over 196608 float4
  const float4* p = reinterpret_cast<const float4*>(parts);
  float4 a = p[i];
  #pragma unroll
  for (int s = 1; s < KSPLIT; ++s) {
    const float4 b = p[(size_t)s * (NROWS * E_DIM / 4) + i];
    a.x += b.x; a.y += b.y; a.z += b.z; a.w += b.w;
  }
  reinterpret_cast<float4*>(dtBC)[i] = a;
  const int m = i / 24;                              // 24 float4 per row
  const int f4 = i - m * 24;
  if (f4 < 16) {                                     // cols 0..63 = dt_in
    unsigned int u0, u1;
    asm("v_cvt_pk_bf16_f32 %0, %1, %2" : "=v"(u0) : "v"(a.x), "v"(a.y));
    asm("v_cvt_pk_bf16_f32 %0, %1, %2" : "=v"(u1) : "v"(a.z), "v"(a.w));
    *reinterpret_cast<uint2*>(&dt_in_bf[(size_t)m * DT_RANK + f4 * 4]) =
        make_uint2(u0, u1);
  }
}

// ---------------------------------------------------------------------------
// Kernel 2 (MFMA): dt[m][d] = softplus(dt_in @ W2^T + b2), M=8192 N=1024 K=64.
// ---------------------------------------------------------------------------
__global__ __launch_bounds__(256)
void k_dtm(const unsigned short* __restrict__ dt_in_bf,
           const unsigned short* __restrict__ W2bf,
           const float* __restrict__ b2, float* __restrict__ dt) {
  const int tid = threadIdx.x;
  const int lane = tid & 63, w = tid >> 6;
  const int r = lane & 15, kq = lane >> 4;
  const int m0 = blockIdx.x * 64 + w * 16;
  const int d0 = blockIdx.y * 64;

  f32x4 acc[4];
  #pragma unroll
  for (int j = 0; j < 4; ++j) acc[j] = (f32x4){0.f, 0.f, 0.f, 0.f};

  #pragma unroll
  for (int ks = 0; ks < 2; ++ks) {
    const bf16x8 af = *reinterpret_cast<const bf16x8*>(
        &dt_in_bf[(size_t)(m0 + r) * DT_RANK + ks * 32 + kq * 8]);
    #pragma unroll
    for (int j = 0; j < 4; ++j) {
      const bf16x8 bf = *reinterpret_cast<const bf16x8*>(
          &W2bf[(size_t)(d0 + j * 16 + r) * DT_RANK + ks * 32 + kq * 8]);
      acc[j] = __builtin_amdgcn_mfma_f32_16x16x32_bf16(af, bf, acc[j], 0, 0, 0);
    }
  }
  #pragma unroll
  for (int j = 0; j < 4; ++j) {
    const float bias = b2[d0 + j * 16 + r];
    #pragma unroll
    for (int i = 0; i < 4; ++i) {
      const float a = acc[j][i] + bias;
      const float sp = (a > 15.f) ? a : __logf(1.f + __expf(a));
      dt[(size_t)(m0 + kq * 4 + i) * D_MODEL + d0 + j * 16 + r] = sp;
    }
  }
}

// ---------------------------------------------------------------------------
// Phase A: per-chunk transfer; 2 d-columns/thread, 3-deep named-scalar
// prefetch rotation (no unroll pragma -> no spill; ~1000cy load lead time).
// Layout of P/U/hst: [b][c][n][d] (d-coalesced).
// ---------------------------------------------------------------------------
__global__ __launch_bounds__(256)
void k_scanA(const float* __restrict__ dt, const float* __restrict__ x,
             const float* __restrict__ dtBC, const float* __restrict__ A_log,
             float* __restrict__ P, float* __restrict__ U) {
  const int d0 = blockIdx.x * 512 + threadIdx.x * 2;
  const int c = blockIdx.y;
  const int b = blockIdx.z;
  const int t0 = c * CH;

  __shared__ float sB[CH][D_STATE];
  for (int idx = threadIdx.x; idx < CH * D_STATE; idx += 256) {
    const int t = idx >> 4, n = idx & 15;
    sB[t][n] = dtBC[(size_t)(b * SEQLEN + t0 + t) * E_DIM + DT_RANK + n];
  }
  __syncthreads();

  float Ar0[D_STATE], Ar1[D_STATE];
  #pragma unroll
  for (int q = 0; q < 4; ++q) {
    const float4 v0 = *reinterpret_cast<const float4*>(
        &A_log[(size_t)d0 * D_STATE + q * 4]);
    const float4 v1 = *reinterpret_cast<const float4*>(
        &A_log[(size_t)(d0 + 1) * D_STATE + q * 4]);
    Ar0[q * 4 + 0] = -__expf(v0.x); Ar0[q * 4 + 1] = -__expf(v0.y);
    Ar0[q * 4 + 2] = -__expf(v0.z); Ar0[q * 4 + 3] = -__expf(v0.w);
    Ar1[q * 4 + 0] = -__expf(v1.x); Ar1[q * 4 + 1] = -__expf(v1.y);
    Ar1[q * 4 + 2] = -__expf(v1.z); Ar1[q * 4 + 3] = -__expf(v1.w);
  }

  float Pr0[D_STATE], Ur0[D_STATE], Pr1[D_STATE], Ur1[D_STATE];
  #pragma unroll
  for (int n = 0; n < D_STATE; ++n) {
    Pr0[n] = 1.f; Ur0[n] = 0.f; Pr1[n] = 1.f; Ur1[n] = 0.f;
  }

  const float* dtp = dt + (size_t)(b * SEQLEN + t0) * D_MODEL + d0;
  const float* xp  = x  + (size_t)(b * SEQLEN + t0) * D_MODEL + d0;

  float2 dv0 = *reinterpret_cast<const float2*>(dtp);
  float2 dv1 = *reinterpret_cast<const float2*>(dtp + D_MODEL);
  float2 dv2 = *reinterpret_cast<const float2*>(dtp + 2 * D_MODEL);
  float2 xv0 = *reinterpret_cast<const float2*>(xp);
  float2 xv1 = *reinterpret_cast<const float2*>(xp + D_MODEL);
  float2 xv2 = *reinterpret_cast<const float2*>(xp + 2 * D_MODEL);

  for (int t = 0; t < CH; ++t) {
    const int tn = (t + 3 < CH) ? (t + 3) : t;      // clamped: harmless reload
    const float2 dn = *reinterpret_cast<const float2*>(
        dtp + (size_t)tn * D_MODEL);
    const float2 xn = *reinterpret_cast<const float2*>(
        xp + (size_t)tn * D_MODEL);
    const float z0 = dv0.x * xv0.x;
    const float z1 = dv0.y * xv0.y;
    #pragma unroll
    for (int n = 0; n < D_STATE; ++n) {
      const float sb = sB[t][n];
      const float e0 = __expf(dv0.x * Ar0[n]);
      const float e1 = __expf(dv0.y * Ar1[n]);
      Ur0[n] = fmaf(e0, Ur0[n], z0 * sb);
      Ur1[n] = fmaf(e1, Ur1[n], z1 * sb);
      Pr0[n] *= e0;
      Pr1[n] *= e1;
    }
    dv0 = dv1; dv1 = dv2; dv2 = dn;
    xv0 = xv1; xv1 = xv2; xv2 = xn;
  }
  const size_t base = (size_t)(b * NCH + c) * (D_STATE * D_MODEL) + d0;
  #pragma unroll
  for (int n = 0; n < D_STATE; ++n) {
    *reinterpret_cast<float2*>(&P[base + (size_t)n * D_MODEL]) =
        make_float2(Pr0[n], Pr1[n]);
    *reinterpret_cast<float2*>(&U[base + (size_t)n * D_MODEL]) =
        make_float2(Ur0[n], Ur1[n]);
  }
}

// ---------------------------------------------------------------------------
// Phase B: inter-chunk scan, batch-8 prefetch.
// ---------------------------------------------------------------------------
__global__ __launch_bounds__(256)
void k_scanB(const float* __restrict__ P, const float* __restrict__ U,
             float* __restrict__ hst) {
  const int idx = blockIdx.x * 256 + threadIdx.x;   // b*16384 + n*1024 + d
  const int b = idx >> 14;
  const int nd = idx & 16383;
  float h = 0.f;
  for (int c0 = 0; c0 < NCH; c0 += 8) {
    float p[8], u[8];
    #pragma unroll
    for (int i = 0; i < 8; ++i) {
      const size_t off = (size_t)(b * NCH + c0 + i) * (D_STATE * D_MODEL) + nd;
      p[i] = P[off]; u[i] = U[off];
    }
    #pragma unroll
    for (int i = 0; i < 8; ++i) {
      const size_t off = (size_t)(b * NCH + c0 + i) * (D_STATE * D_MODEL) + nd;
      hst[off] = h;
      h = fmaf(p[i], h, u[i]);
    }
  }
}

// ---------------------------------------------------------------------------
// Phase C: replay within chunk from hst; 2 d-columns/thread, 3-deep prefetch.
// ---------------------------------------------------------------------------
__global__ __launch_bounds__(256)
void k_scanC(const float* __restrict__ dt, const float* __restrict__ x,
             const float* __restrict__ dtBC, const float* __restrict__ A_log,
             const float* __restrict__ Dp, const float* __restrict__ hst,
             float* __restrict__ y) {
  const int d0 = blockIdx.x * 512 + threadIdx.x * 2;
  const int c = blockIdx.y;
  const int b = blockIdx.z;
  const int t0 = c * CH;

  __shared__ float sBC[CH][2 * D_STATE];   // [t][0..15]=B, [t][16..31]=C
  for (int idx = threadIdx.x; idx < CH * 2 * D_STATE; idx += 256) {
    const int t = idx >> 5, j = idx & 31;
    sBC[t][j] = dtBC[(size_t)(b * SEQLEN + t0 + t) * E_DIM + DT_RANK + j];
  }
  __syncthreads();

  float Ar0[D_STATE], Ar1[D_STATE];
  #pragma unroll
  for (int q = 0; q < 4; ++q) {
    const float4 v0 = *reinterpret_cast<const float4*>(
        &A_log[(size_t)d0 * D_STATE + q * 4]);
    const float4 v1 = *reinterpret_cast<const float4*>(
        &A_log[(size_t)(d0 + 1) * D_STATE + q * 4]);
    Ar0[q * 4 + 0] = -__expf(v0.x); Ar0[q * 4 + 1] = -__expf(v0.y);
    Ar0[q * 4 + 2] = -__expf(v0.z); Ar0[q * 4 + 3] = -__expf(v0.w);
    Ar1[q * 4 + 0] = -__expf(v1.x); Ar1[q * 4 + 1] = -__expf(v1.y);
    Ar1[q * 4 + 2] = -__expf(v1.z); Ar1[q * 4 + 3] = -__expf(v1.w);
  }
  const float2 Dv = *reinterpret_cast<const float2*>(&Dp[d0]);

  float h0[D_STATE], h1[D_STATE];
  const size_t hbase = (size_t)(b * NCH + c) * (D_STATE * D_MODEL) + d0;
  #pragma unroll
  for (int n = 0; n < D_STATE; ++n) {
    const float2 hv = *reinterpret_cast<const float2*>(
        &hst[hbase + (size_t)n * D_MODEL]);
    h0[n] = hv.x; h1[n] = hv.y;
  }

  const float* dtp = dt + (size_t)(b * SEQLEN + t0) * D_MODEL + d0;
  const float* xp  = x  + (size_t)(b * SEQLEN + t0) * D_MODEL + d0;
  float* yp        = y  + (size_t)(b * SEQLEN + t0) * D_MODEL + d0;

  float2 dv0 = *reinterpret_cast<const float2*>(dtp);
  float2 dv1 = *reinterpret_cast<const float2*>(dtp + D_MODEL);
  float2 dv2 = *reinterpret_cast<const float2*>(dtp + 2 * D_MODEL);
  float2 xv0 = *reinterpret_cast<const float2*>(xp);
  float2 xv1 = *reinterpret_cast<const float2*>(xp + D_MODEL);
  float2 xv2 = *reinterpret_cast<const float2*>(xp + 2 * D_MODEL);

  for (int t = 0; t < CH; ++t) {
    const int tn = (t + 3 < CH) ? (t + 3) : t;      // clamped: harmless reload
    const float2 dn = *reinterpret_cast<const float2*>(
        dtp + (size_t)tn * D_MODEL);
    const float2 xn = *reinterpret_cast<const float2*>(
        xp + (size_t)tn * D_MODEL);
    const float z0 = dv0.x * xv0.x;
    const float z1 = dv0.y * xv0.y;
    float acc0 = 0.f, acc1 = 0.f;
    #pragma unroll
    for (int n = 0; n < D_STATE; ++n) {
      const float sb = sBC[t][n];
      const float sc = sBC[t][D_STATE + n];
      const float e0 = __expf(dv0.x * Ar0[n]);
      const float e1 = __expf(dv0.y * Ar1[n]);
      h0[n] = fmaf(e0, h0[n], z0 * sb);
      h1[n] = fmaf(e1, h1[n], z1 * sb);
      acc0 = fmaf(h0[n], sc, acc0);
      acc1 = fmaf(h1[n], sc, acc1);
    }
    *reinterpret_cast<float2*>(yp + (size_t)t * D_MODEL) =
        make_float2(fmaf(xv0.x, Dv.x, acc0), fmaf(xv0.y, Dv.y, acc1));
    dv0 = dv1; dv1 = dv2; dv2 = dn;
    xv0 = xv1; xv1 = xv2; xv2 = xn;
  }
}

extern "C" void kernel_launch(void* const* d_in, const int* in_sizes, int n_in,
                              void* d_out, int out_size, void* d_ws, size_t ws_size,
                              hipStream_t stream) {
  const float* x     = (const float*)d_in[0];
  const float* A_log = (const float*)d_in[1];
  const float* Dp    = (const float*)d_in[2];
  const float* W2    = (const float*)d_in[3];   // dt_proj_w (1024,64)
  const float* b2    = (const float*)d_in[4];   // dt_proj_b (1024,)
  const float* Wx    = (const float*)d_in[5];   // x_to_dtBC_w (96,1024)
  float* out = (float*)d_out;

  float* ws = (float*)d_ws;
  // layout (floats):
  float* dtBC  = ws;                    //   786,432
  float* dtbuf = ws +   786432;         // 8,388,608
  float* P     = ws +  9175040;         // 4,194,304
  float* U     = ws + 13369344;         // 4,194,304
  float* hst   = ws + 17563648;         // 4,194,304  (end 21,757,952 = 87 MB)
  // aliases:
  float* parts = P;                     // 3,145,728 <= P span, dead post-reduce
  unsigned short* Wxbf     = (unsigned short*)hst;             //  98,304 bf16
  unsigned short* W2bf     = (unsigned short*)(hst + 49152);   //  65,536 bf16
  unsigned short* dt_in_bf = (unsigned short*)(hst + 82944);   // 524,288 bf16
  // (all dead before k_scanB writes hst)

  hipLaunchKernelGGL(k_prep, dim3(640), dim3(256), 0, stream, Wx, W2, Wxbf, W2bf);
  hipLaunchKernelGGL(k_gemm1, dim3(NROWS / 64, KSPLIT), dim3(256), 0, stream,
                     x, Wxbf, parts);
  hipLaunchKernelGGL(k_reduce, dim3(NROWS * E_DIM / 4 / 256), dim3(256), 0,
                     stream, parts, dtBC, dt_in_bf);
  hipLaunchKernelGGL(k_dtm, dim3(NROWS / 64, D_MODEL / 64), dim3(256), 0,
                     stream, dt_in_bf, W2bf, b2, dtbuf);
  hipLaunchKernelGGL(k_scanA, dim3(D_MODEL / 512, NCH, BATCH), dim3(256),
                     0, stream, dtbuf, x, dtBC, A_log, P, U);
  hipLaunchKernelGGL(k_scanB, dim3((BATCH * D_STATE * D_MODEL) / 256),
                     dim3(256), 0, stream, P, U, hst);
  hipLaunchKernelGGL(k_scanC, dim3(D_MODEL / 512, NCH, BATCH), dim3(256),
                     0, stream, dtbuf, x, dtBC, A_log, Dp, hst, out);
}

// Round 12
// 190.986 us; speedup vs baseline: 1.0755x; 1.0755x over previous
//
#include <hip/hip_runtime.h>

#define D_MODEL 1024
#define D_STATE 16
#define DT_RANK 64
#define BATCH 2
#define SEQLEN 4096
#define NROWS (BATCH * SEQLEN)           // 8192
#define E_DIM 96
#define CH 32
#define NCH (SEQLEN / CH)                // 128

typedef short bf16x8 __attribute__((ext_vector_type(8)));
typedef float f32x4 __attribute__((ext_vector_type(4)));

// ---------------------------------------------------------------------------
// k_prep: Wx (96x1024 fp32) -> Wxbf (bf16 RNE); W2 (1024x64) -> W2bf.
// ---------------------------------------------------------------------------
__global__ __launch_bounds__(256)
void k_prep(const float* __restrict__ Wx, const float* __restrict__ W2,
            unsigned short* __restrict__ Wxbf, unsigned short* __restrict__ W2bf) {
  const int bid = blockIdx.x;
  if (bid < 384) {                       // 96*1024 = 98304
    const int idx = bid * 256 + threadIdx.x;
    unsigned int u = __float_as_uint(Wx[idx]);
    u = (u + 0x7fffu + ((u >> 16) & 1u)) >> 16;   // RNE
    Wxbf[idx] = (unsigned short)u;
  } else {                               // 1024*64 = 65536
    const int idx = (bid - 384) * 256 + threadIdx.x;
    unsigned int u = __float_as_uint(W2[idx]);
    u = (u + 0x7fffu + ((u >> 16) & 1u)) >> 16;   // RNE
    W2bf[idx] = (unsigned short)u;
  }
}

// ---------------------------------------------------------------------------
// Kernel 1: dtBC = x @ Wx^T via bf16 MFMA 16x16x32, LDS-staged operands.
// Block: 4 waves, M-tile 64, KSPLIT=4. Rows padded to 72 bf16 (144B).
// D layout: row=(l>>4)*4+i, col=l&15  [m89-verified]
// ---------------------------------------------------------------------------
#define KSPLIT 4
#define KSEG (D_MODEL / KSPLIT)          // 256

__global__ __launch_bounds__(256)
void k_gemm1(const float* __restrict__ x, const unsigned short* __restrict__ Wxbf,
             float* __restrict__ parts) {
  __shared__ unsigned short sXb[64][72];   // 9.2 KB
  __shared__ unsigned short sWb[96][72];   // 13.8 KB
  const int tid = threadIdx.x;
  const int lane = tid & 63, w = tid >> 6;
  const int r = lane & 15, kq = lane >> 4;
  const int m0 = blockIdx.x * 64;
  const int ks0 = blockIdx.y * KSEG;

  f32x4 acc[6];
  #pragma unroll
  for (int j = 0; j < 6; ++j) acc[j] = (f32x4){0.f, 0.f, 0.f, 0.f};

  for (int kt = 0; kt < KSEG; kt += 64) {
    #pragma unroll
    for (int s = 0; s < 4; ++s) {
      const int f = s * 256 + tid;
      const int row = f >> 4, k4 = f & 15;
      const float4 v = *reinterpret_cast<const float4*>(
          &x[(size_t)(m0 + row) * D_MODEL + ks0 + kt + k4 * 4]);
      unsigned int u0, u1;
      asm("v_cvt_pk_bf16_f32 %0, %1, %2" : "=v"(u0) : "v"(v.x), "v"(v.y));
      asm("v_cvt_pk_bf16_f32 %0, %1, %2" : "=v"(u1) : "v"(v.z), "v"(v.w));
      *reinterpret_cast<uint2*>(&sXb[row][k4 * 4]) = make_uint2(u0, u1);
    }
    #pragma unroll
    for (int s = 0; s < 3; ++s) {
      const int f = s * 256 + tid;
      const int e = f >> 3, k8 = f & 7;
      *reinterpret_cast<uint4*>(&sWb[e][k8 * 8]) =
          *reinterpret_cast<const uint4*>(
              &Wxbf[(size_t)e * D_MODEL + ks0 + kt + k8 * 8]);
    }
    __syncthreads();
    #pragma unroll
    for (int ks = 0; ks < 2; ++ks) {
      const bf16x8 af = *reinterpret_cast<const bf16x8*>(
          &sXb[w * 16 + r][ks * 32 + kq * 8]);
      #pragma unroll
      for (int j = 0; j < 6; ++j) {
        const bf16x8 bf = *reinterpret_cast<const bf16x8*>(
            &sWb[j * 16 + r][ks * 32 + kq * 8]);
        acc[j] = __builtin_amdgcn_mfma_f32_16x16x32_bf16(af, bf, acc[j], 0, 0, 0);
      }
    }
    __syncthreads();
  }
  float* op = parts + (size_t)blockIdx.y * (NROWS * E_DIM);
  #pragma unroll
  for (int j = 0; j < 6; ++j)
    #pragma unroll
    for (int i = 0; i < 4; ++i)
      op[(size_t)(m0 + w * 16 + kq * 4 + i) * E_DIM + j * 16 + r] = acc[j][i];
}

// Sum KSPLIT partials -> dtBC (fp32); also emit dt_in_bf = bf16 of cols 0..63.
__global__ __launch_bounds__(256)
void k_reduce(const float* __restrict__ parts, float* __restrict__ dtBC,
              unsigned short* __restrict__ dt_in_bf) {
  const int i = blockIdx.x * 256 + threadIdx.x;     // over 196608 float4
  const float4* p = reinterpret_cast<const float4*>(parts);
  float4 a = p[i];
  #pragma unroll
  for (int s = 1; s < KSPLIT; ++s) {
    const float4 b = p[(size_t)s * (NROWS * E_DIM / 4) + i];
    a.x += b.x; a.y += b.y; a.z += b.z; a.w += b.w;
  }
  reinterpret_cast<float4*>(dtBC)[i] = a;
  const int m = i / 24;                              // 24 float4 per row
  const int f4 = i - m * 24;
  if (f4 < 16) {                                     // cols 0..63 = dt_in
    unsigned int u0, u1;
    asm("v_cvt_pk_bf16_f32 %0, %1, %2" : "=v"(u0) : "v"(a.x), "v"(a.y));
    asm("v_cvt_pk_bf16_f32 %0, %1, %2" : "=v"(u1) : "v"(a.z), "v"(a.w));
    *reinterpret_cast<uint2*>(&dt_in_bf[(size_t)m * DT_RANK + f4 * 4]) =
        make_uint2(u0, u1);
  }
}

// ---------------------------------------------------------------------------
// Kernel 2 (MFMA): dt[m][d] = softplus(dt_in @ W2^T + b2), M=8192 N=1024 K=64.
// ---------------------------------------------------------------------------
__global__ __launch_bounds__(256)
void k_dtm(const unsigned short* __restrict__ dt_in_bf,
           const unsigned short* __restrict__ W2bf,
           const float* __restrict__ b2, float* __restrict__ dt) {
  const int tid = threadIdx.x;
  const int lane = tid & 63, w = tid >> 6;
  const int r = lane & 15, kq = lane >> 4;
  const int m0 = blockIdx.x * 64 + w * 16;
  const int d0 = blockIdx.y * 64;

  f32x4 acc[4];
  #pragma unroll
  for (int j = 0; j < 4; ++j) acc[j] = (f32x4){0.f, 0.f, 0.f, 0.f};

  #pragma unroll
  for (int ks = 0; ks < 2; ++ks) {
    const bf16x8 af = *reinterpret_cast<const bf16x8*>(
        &dt_in_bf[(size_t)(m0 + r) * DT_RANK + ks * 32 + kq * 8]);
    #pragma unroll
    for (int j = 0; j < 4; ++j) {
      const bf16x8 bf = *reinterpret_cast<const bf16x8*>(
          &W2bf[(size_t)(d0 + j * 16 + r) * DT_RANK + ks * 32 + kq * 8]);
      acc[j] = __builtin_amdgcn_mfma_f32_16x16x32_bf16(af, bf, acc[j], 0, 0, 0);
    }
  }
  #pragma unroll
  for (int j = 0; j < 4; ++j) {
    const float bias = b2[d0 + j * 16 + r];
    #pragma unroll
    for (int i = 0; i < 4; ++i) {
      const float a = acc[j][i] + bias;
      const float sp = (a > 15.f) ? a : __logf(1.f + __expf(a));
      dt[(size_t)(m0 + kq * 4 + i) * D_MODEL + d0 + j * 16 + r] = sp;
    }
  }
}

// ---------------------------------------------------------------------------
// Phase A (n-split): wave = 32 d-columns x 2 n-halves (lanes 0-31: n 0-7,
// lanes 32-63: n 8-15). 8 states/thread. Grid 2048 blocks -> 32 waves/CU.
// R9's plain 1-deep pipeline. P/U layout [b][c][n][d] unchanged.
// ---------------------------------------------------------------------------
__global__ __launch_bounds__(256)
void k_scanA(const float* __restrict__ dt, const float* __restrict__ x,
             const float* __restrict__ dtBC, const float* __restrict__ A_log,
             float* __restrict__ P, float* __restrict__ U) {
  const int tid = threadIdx.x;
  const int w = tid >> 6, lane = tid & 63;
  const int dl = lane & 31, hn = lane >> 5;
  const int d0 = blockIdx.x * 128 + w * 32 + dl;
  const int nb = hn * 8;
  const int c = blockIdx.y;
  const int b = blockIdx.z;
  const int t0 = c * CH;

  __shared__ float sB[CH][D_STATE];
  for (int idx = tid; idx < CH * D_STATE; idx += 256) {
    const int t = idx >> 4, n = idx & 15;
    sB[t][n] = dtBC[(size_t)(b * SEQLEN + t0 + t) * E_DIM + DT_RANK + n];
  }
  __syncthreads();

  float Ar[8];
  {
    const float4 v0 = *reinterpret_cast<const float4*>(
        &A_log[(size_t)d0 * D_STATE + nb]);
    const float4 v1 = *reinterpret_cast<const float4*>(
        &A_log[(size_t)d0 * D_STATE + nb + 4]);
    Ar[0] = -__expf(v0.x); Ar[1] = -__expf(v0.y);
    Ar[2] = -__expf(v0.z); Ar[3] = -__expf(v0.w);
    Ar[4] = -__expf(v1.x); Ar[5] = -__expf(v1.y);
    Ar[6] = -__expf(v1.z); Ar[7] = -__expf(v1.w);
  }

  float Pr[8], Ur[8];
  #pragma unroll
  for (int n = 0; n < 8; ++n) { Pr[n] = 1.f; Ur[n] = 0.f; }

  const float* dtp = dt + (size_t)(b * SEQLEN + t0) * D_MODEL + d0;
  const float* xp  = x  + (size_t)(b * SEQLEN + t0) * D_MODEL + d0;

  float dtv = dtp[0];
  float xv  = xp[0];
  for (int t = 0; t < CH; ++t) {
    float dtn = 0.f, xn = 0.f;
    if (t + 1 < CH) {
      dtn = dtp[(size_t)(t + 1) * D_MODEL];
      xn  = xp[(size_t)(t + 1) * D_MODEL];
    }
    const float z = dtv * xv;
    #pragma unroll
    for (int n = 0; n < 8; ++n) {
      const float e = __expf(dtv * Ar[n]);
      Ur[n] = fmaf(e, Ur[n], z * sB[t][nb + n]);
      Pr[n] *= e;
    }
    dtv = dtn; xv = xn;
  }
  const size_t base = (size_t)(b * NCH + c) * (D_STATE * D_MODEL) + d0;
  #pragma unroll
  for (int n = 0; n < 8; ++n) {
    P[base + (size_t)(nb + n) * D_MODEL] = Pr[n];
    U[base + (size_t)(nb + n) * D_MODEL] = Ur[n];
  }
}

// ---------------------------------------------------------------------------
// Phase B: inter-chunk scan, batch-8 prefetch.
// ---------------------------------------------------------------------------
__global__ __launch_bounds__(256)
void k_scanB(const float* __restrict__ P, const float* __restrict__ U,
             float* __restrict__ hst) {
  const int idx = blockIdx.x * 256 + threadIdx.x;   // b*16384 + n*1024 + d
  const int b = idx >> 14;
  const int nd = idx & 16383;
  float h = 0.f;
  for (int c0 = 0; c0 < NCH; c0 += 8) {
    float p[8], u[8];
    #pragma unroll
    for (int i = 0; i < 8; ++i) {
      const size_t off = (size_t)(b * NCH + c0 + i) * (D_STATE * D_MODEL) + nd;
      p[i] = P[off]; u[i] = U[off];
    }
    #pragma unroll
    for (int i = 0; i < 8; ++i) {
      const size_t off = (size_t)(b * NCH + c0 + i) * (D_STATE * D_MODEL) + nd;
      hst[off] = h;
      h = fmaf(p[i], h, u[i]);
    }
  }
}

// ---------------------------------------------------------------------------
// Phase C (n-split): same lane mapping as scanA; per-step cross-half add via
// __shfl_xor(acc,32); y written by the hn==0 half only.
// ---------------------------------------------------------------------------
__global__ __launch_bounds__(256)
void k_scanC(const float* __restrict__ dt, const float* __restrict__ x,
             const float* __restrict__ dtBC, const float* __restrict__ A_log,
             const float* __restrict__ Dp, const float* __restrict__ hst,
             float* __restrict__ y) {
  const int tid = threadIdx.x;
  const int w = tid >> 6, lane = tid & 63;
  const int dl = lane & 31, hn = lane >> 5;
  const int d0 = blockIdx.x * 128 + w * 32 + dl;
  const int nb = hn * 8;
  const int c = blockIdx.y;
  const int b = blockIdx.z;
  const int t0 = c * CH;

  __shared__ float sBC[CH][2 * D_STATE];   // [t][0..15]=B, [t][16..31]=C
  for (int idx = tid; idx < CH * 2 * D_STATE; idx += 256) {
    const int t = idx >> 5, j = idx & 31;
    sBC[t][j] = dtBC[(size_t)(b * SEQLEN + t0 + t) * E_DIM + DT_RANK + j];
  }
  __syncthreads();

  float Ar[8];
  {
    const float4 v0 = *reinterpret_cast<const float4*>(
        &A_log[(size_t)d0 * D_STATE + nb]);
    const float4 v1 = *reinterpret_cast<const float4*>(
        &A_log[(size_t)d0 * D_STATE + nb + 4]);
    Ar[0] = -__expf(v0.x); Ar[1] = -__expf(v0.y);
    Ar[2] = -__expf(v0.z); Ar[3] = -__expf(v0.w);
    Ar[4] = -__expf(v1.x); Ar[5] = -__expf(v1.y);
    Ar[6] = -__expf(v1.z); Ar[7] = -__expf(v1.w);
  }
  const float Dv = Dp[d0];

  float h[8];
  const size_t hbase = (size_t)(b * NCH + c) * (D_STATE * D_MODEL) + d0;
  #pragma unroll
  for (int n = 0; n < 8; ++n) h[n] = hst[hbase + (size_t)(nb + n) * D_MODEL];

  const float* dtp = dt + (size_t)(b * SEQLEN + t0) * D_MODEL + d0;
  const float* xp  = x  + (size_t)(b * SEQLEN + t0) * D_MODEL + d0;
  float* yp        = y  + (size_t)(b * SEQLEN + t0) * D_MODEL + d0;

  float dtv = dtp[0];
  float xv  = xp[0];
  for (int t = 0; t < CH; ++t) {
    float dtn = 0.f, xn = 0.f;
    if (t + 1 < CH) {
      dtn = dtp[(size_t)(t + 1) * D_MODEL];
      xn  = xp[(size_t)(t + 1) * D_MODEL];
    }
    const float z = dtv * xv;
    float acc = 0.f;
    #pragma unroll
    for (int n = 0; n < 8; ++n) {
      const float e = __expf(dtv * Ar[n]);
      h[n] = fmaf(e, h[n], z * sBC[t][nb + n]);
      acc = fmaf(h[n], sBC[t][D_STATE + nb + n], acc);
    }
    acc += __shfl_xor(acc, 32, 64);
    if (hn == 0)
      yp[(size_t)t * D_MODEL] = fmaf(xv, Dv, acc);
    dtv = dtn; xv = xn;
  }
}

extern "C" void kernel_launch(void* const* d_in, const int* in_sizes, int n_in,
                              void* d_out, int out_size, void* d_ws, size_t ws_size,
                              hipStream_t stream) {
  const float* x     = (const float*)d_in[0];
  const float* A_log = (const float*)d_in[1];
  const float* Dp    = (const float*)d_in[2];
  const float* W2    = (const float*)d_in[3];   // dt_proj_w (1024,64)
  const float* b2    = (const float*)d_in[4];   // dt_proj_b (1024,)
  const float* Wx    = (const float*)d_in[5];   // x_to_dtBC_w (96,1024)
  float* out = (float*)d_out;

  float* ws = (float*)d_ws;
  // layout (floats):
  float* dtBC  = ws;                    //   786,432
  float* dtbuf = ws +   786432;         // 8,388,608
  float* P     = ws +  9175040;         // 4,194,304
  float* U     = ws + 13369344;         // 4,194,304
  float* hst   = ws + 17563648;         // 4,194,304  (end 21,757,952 = 87 MB)
  // aliases:
  float* parts = P;                     // 3,145,728 <= P span, dead post-reduce
  unsigned short* Wxbf     = (unsigned short*)hst;             //  98,304 bf16
  unsigned short* W2bf     = (unsigned short*)(hst + 49152);   //  65,536 bf16
  unsigned short* dt_in_bf = (unsigned short*)(hst + 82944);   // 524,288 bf16
  // (all dead before k_scanB writes hst)

  hipLaunchKernelGGL(k_prep, dim3(640), dim3(256), 0, stream, Wx, W2, Wxbf, W2bf);
  hipLaunchKernelGGL(k_gemm1, dim3(NROWS / 64, KSPLIT), dim3(256), 0, stream,
                     x, Wxbf, parts);
  hipLaunchKernelGGL(k_reduce, dim3(NROWS * E_DIM / 4 / 256), dim3(256), 0,
                     stream, parts, dtBC, dt_in_bf);
  hipLaunchKernelGGL(k_dtm, dim3(NROWS / 64, D_MODEL / 64), dim3(256), 0,
                     stream, dt_in_bf, W2bf, b2, dtbuf);
  hipLaunchKernelGGL(k_scanA, dim3(D_MODEL / 128, NCH, BATCH), dim3(256),
                     0, stream, dtbuf, x, dtBC, A_log, P, U);
  hipLaunchKernelGGL(k_scanB, dim3((BATCH * D_STATE * D_MODEL) / 256),
                     dim3(256), 0, stream, P, U, hst);
  hipLaunchKernelGGL(k_scanC, dim3(D_MODEL / 128, NCH, BATCH), dim3(256),
                     0, stream, dtbuf, x, dtBC, A_log, Dp, hst, out);
}